// Round 5
// baseline (233.478 us; speedup 1.0000x reference)
//
#include <hip/hip_runtime.h>

#define BB 32
#define LL 1024
#define HH 384
#define H4 (HH / 4)   // 96 float4 per row
#define NT 256        // threads per block
#define NW (NT / 64)  // waves per block
#define NB 32         // slabs per batch; grid = (NB, BB) = 1024 blocks = 4/CU
#define SMAX 256      // max slab length (T <= 7168 -> slab <= 224)

typedef float f4 __attribute__((ext_vector_type(4)));

__global__ __launch_bounds__(NT) void lenreg_kernel(
    const float* __restrict__ ehs,   // (B, L, H) f32
    const int* __restrict__ dur,     // (B, L) i32
    float* __restrict__ out,         // (B, T, H) f32
    float* __restrict__ mask,        // (B, T) f32
    int T)
{
    __shared__ int scum[LL];     // inclusive cumsum of durations for this batch
    __shared__ int wsum[NW];     // per-wave totals
    __shared__ int sidx[SMAX];   // source token index per t in this slab (-1 = masked)

    const int tid  = threadIdx.x;
    const int lane = tid & 63;
    const int wid  = tid >> 6;
    const int b    = blockIdx.y;

    const int slab = (T + NB - 1) / NB;          // uniform across grid
    const int ts   = blockIdx.x * slab;
    const int te   = (ts + slab < T) ? (ts + slab) : T;
    if (ts >= te) return;                        // block-uniform: safe before barriers
    const int n    = te - ts;                    // <= SMAX

    // ---- cumsum of durations[b,:]: wave shfl scan, 2 barriers total ----
    int4 d = ((const int4*)(dur + (size_t)b * LL))[tid];
    const int p0 = d.x;
    const int p1 = p0 + d.y;
    const int p2 = p1 + d.z;
    const int p3 = p2 + d.w;

    int v = p3;
    #pragma unroll
    for (int off = 1; off < 64; off <<= 1) {
        const int nn = __shfl_up(v, off, 64);
        if (lane >= off) v += nn;
    }
    if (lane == 63) wsum[wid] = v;
    __syncthreads();

    int woff = 0, total = 0;
    #pragma unroll
    for (int w = 0; w < NW; ++w) {
        const int s = wsum[w];
        woff  += (w < wid) ? s : 0;
        total += s;
    }

    const int excl = woff + v - p3;   // exclusive prefix for this thread's 4 tokens
    scum[4 * tid + 0] = excl + p0;
    scum[4 * tid + 1] = excl + p1;
    scum[4 * tid + 2] = excl + p2;
    scum[4 * tid + 3] = excl + p3;
    __syncthreads();

    // ---- per-slab index map: branchless pow2 lower-bound, one pass ----
    if (tid < n) {
        const int t = ts + tid;
        int pos = 0;
        #pragma unroll
        for (int step = LL / 2; step > 0; step >>= 1) {
            if (scum[pos + step - 1] <= t) pos += step;   // max probe idx = 1023
        }
        pos = (pos < LL - 1) ? pos : (LL - 1);
        sidx[tid] = (t < total) ? pos : -1;               // -1 encodes masked tail
        mask[(size_t)b * T + t] = (t < total) ? 1.0f : 0.0f;
    }
    __syncthreads();

    // ---- single uninterrupted streaming phase: contiguous ~n*1.5KB extent ----
    const f4* __restrict__ src = (const f4*)(ehs + (size_t)b * LL * HH);
    f4* __restrict__ ob = (f4*)out + ((size_t)b * T + ts) * (size_t)H4;
    const int wmax = n * H4;
    const f4 zero4 = (f4){0.f, 0.f, 0.f, 0.f};

    #pragma unroll 4
    for (int w = tid; w < wmax; w += NT) {
        const int tl  = w / H4;          // constant div -> magic mul
        const int vv  = w - tl * H4;
        const int idx = sidx[tl];        // read-only LDS, no barrier needed
        f4 val = zero4;
        if (idx >= 0) val = src[(size_t)idx * H4 + vv];
        __builtin_nontemporal_store(val, &ob[w]);
    }
}

extern "C" void kernel_launch(void* const* d_in, const int* in_sizes, int n_in,
                              void* d_out, int out_size, void* d_ws, size_t ws_size,
                              hipStream_t stream) {
    const float* ehs = (const float*)d_in[0];
    const int*   dur = (const int*)d_in[1];

    // out_size = B*T*H + B*T = B*T*(H+1)
    const int T = out_size / (BB * (HH + 1));

    float* out  = (float*)d_out;
    float* mask = (float*)d_out + (size_t)BB * T * HH;

    dim3 grid(NB, BB);
    dim3 block(NT);
    lenreg_kernel<<<grid, block, 0, stream>>>(ehs, dur, out, mask, T);
}

// Round 6
// 227.800 us; speedup vs baseline: 1.0249x; 1.0249x over previous
//
#include <hip/hip_runtime.h>

#define BB 32
#define LL 1024
#define HH 384
#define H4 (HH / 4)   // 96 float4 per row
#define TT 64         // t-positions per block
#define NT 256        // threads per block
#define NW (NT / 64)  // waves per block
#define WPT (TT * H4 / NT)  // float4 per thread in a full tile = 24

typedef float f4 __attribute__((ext_vector_type(4)));   // native vector: nt-store OK

__global__ __launch_bounds__(NT) void lenreg_kernel(
    const float* __restrict__ ehs,   // (B, L, H) f32
    const int* __restrict__ dur,     // (B, L) i32
    float* __restrict__ out,         // (B, T, H) f32
    float* __restrict__ mask,        // (B, T) f32
    int T)
{
    __shared__ int scum[LL];     // inclusive cumsum of durations for this batch
    __shared__ int wsum[NW];     // per-wave totals
    __shared__ int sidx[TT];     // source token index per t in this tile

    const int tid  = threadIdx.x;
    const int lane = tid & 63;
    const int wid  = tid >> 6;
    const int b    = blockIdx.y;
    const int t0   = blockIdx.x * TT;

    // ---- cumsum of durations[b,:]: wave-level shfl scan, only 3 barriers ----
    int4 d = ((const int4*)(dur + (size_t)b * LL))[tid];
    const int p0 = d.x;
    const int p1 = p0 + d.y;
    const int p2 = p1 + d.z;
    const int p3 = p2 + d.w;

    // inclusive scan of p3 across the 64-lane wave (no barriers)
    int v = p3;
    #pragma unroll
    for (int off = 1; off < 64; off <<= 1) {
        const int n = __shfl_up(v, off, 64);
        if (lane >= off) v += n;
    }
    if (lane == 63) wsum[wid] = v;
    __syncthreads();

    int woff = 0, total = 0;
    #pragma unroll
    for (int w = 0; w < NW; ++w) {
        const int s = wsum[w];
        woff  += (w < wid) ? s : 0;
        total += s;
    }

    const int excl = woff + v - p3;   // exclusive prefix for this thread's 4 tokens
    scum[4 * tid + 0] = excl + p0;
    scum[4 * tid + 1] = excl + p1;
    scum[4 * tid + 2] = excl + p2;
    scum[4 * tid + 3] = excl + p3;
    __syncthreads();

    // ---- branchless pow2 lower-bound: pos = #(cum <= t), then clamp ----
    if (tid < TT) {
        const int t = t0 + tid;
        int pos = 0;
        #pragma unroll
        for (int step = LL / 2; step > 0; step >>= 1) {
            if (scum[pos + step - 1] <= t) pos += step;   // max probe = 1023, exact
        }
        sidx[tid] = (pos < LL - 1) ? pos : (LL - 1);
        if (t < T) mask[(size_t)b * T + t] = (t < total) ? 1.0f : 0.0f;
    }
    __syncthreads();

    // ---- gather + store ----
    const f4* __restrict__ src = (const f4*)(ehs + (size_t)b * LL * HH);
    f4* __restrict__ ob = (f4*)out + ((size_t)b * T + t0) * (size_t)H4;

    const int tlim = (T < total) ? T : total;
    if (t0 + TT <= tlim) {
        // fast path: every t in the tile is live -> branchless, fully unrolled,
        // idx reads hoisted, non-temporal stores (write stream has no reuse)
        int idxr[WPT];
        #pragma unroll
        for (int i = 0; i < WPT; ++i) {
            idxr[i] = sidx[(tid + i * NT) / H4];
        }
        #pragma unroll
        for (int i = 0; i < WPT; ++i) {
            const int w  = tid + i * NT;
            const int tl = w / H4;           // compile-time magic-mul
            const int vv = w - tl * H4;
            const f4 val = src[(size_t)idxr[i] * H4 + vv];
            __builtin_nontemporal_store(val, &ob[w]);
        }
    } else {
        // tail path: predicated
        const int tend = (T < t0 + TT) ? T : (t0 + TT);
        const int wmax = (tend > t0) ? (tend - t0) * H4 : 0;
        const f4 zero4 = (f4){0.f, 0.f, 0.f, 0.f};
        for (int w = tid; w < wmax; w += NT) {
            const int tl = w / H4;
            const int vv = w - tl * H4;
            const int t  = t0 + tl;
            f4 val = zero4;
            if (t < total) val = src[(size_t)sidx[tl] * H4 + vv];
            __builtin_nontemporal_store(val, &ob[w]);
        }
    }
}

extern "C" void kernel_launch(void* const* d_in, const int* in_sizes, int n_in,
                              void* d_out, int out_size, void* d_ws, size_t ws_size,
                              hipStream_t stream) {
    const float* ehs = (const float*)d_in[0];
    const int*   dur = (const int*)d_in[1];

    // out_size = B*T*H + B*T = B*T*(H+1)
    const int T = out_size / (BB * (HH + 1));

    float* out  = (float*)d_out;
    float* mask = (float*)d_out + (size_t)BB * T * HH;

    dim3 grid((T + TT - 1) / TT, BB);
    dim3 block(NT);
    lenreg_kernel<<<grid, block, 0, stream>>>(ehs, dur, out, mask, T);
}